// Round 21
// baseline (776.197 us; speedup 1.0000x reference)
//
#include <hip/hip_runtime.h>

constexpr int SP = 16*56*56;      // 50176 spatial per batch
constexpr int P  = 2*SP;          // 100352 positions
constexpr float EPSV = 1e-5f;
constexpr float INVP = 1.f/100352.f;

constexpr size_t SZ_A   = (size_t)2*64*SP;   // 6422528
constexpr size_t OFF_A  = 0;
constexpr size_t OFF_C  = SZ_A;
constexpr size_t OFF_ST = OFF_C + SZ_A;      // 4096 floats of stats
constexpr size_t OFF_P1 = 0;        // pass1 partials (inside dead A region)
constexpr size_t OFF_P2 = 65536;    // attn partials (inside dead A region)

// ---------------- down-projection 128->64 + bn1 stats (128-pos tile, 4 c-chunks of 32) ----------------
__global__ void __launch_bounds__(256) kern_down(
    const float* __restrict__ x, const float* __restrict__ w,
    float* __restrict__ A, float* __restrict__ st)
{
  __shared__ float xs[32*128];      // [c-local][p]  16 KB
  __shared__ float wt[64*33];       // [o][c-local]  8.25 KB
  __shared__ float ssum[64], ssq[64];
  const int t = threadIdx.x;
  if (t < 64) { ssum[t] = 0.f; ssq[t] = 0.f; }
  const int p0 = blockIdx.x * 128;            // 784 blocks
  const int n = p0 / SP, rem = p0 % SP;
  const float* xb = x + (size_t)n*128*SP + rem;
  const int og = t & 15, pg = t >> 4;         // o = og + 16*i, p = pg*8 + j
  float acc[4][8] = {};
  for (int ck = 0; ck < 4; ++ck) {
    __syncthreads();
    for (int e4 = t; e4 < 32*32; e4 += 256) {
      int c = e4 >> 5, p4 = (e4 & 31)*4;
      float4 v = *reinterpret_cast<const float4*>(xb + (size_t)(ck*32+c)*SP + p4);
      *reinterpret_cast<float4*>(&xs[c*128 + p4]) = v;
    }
    for (int e4 = t; e4 < 64*8; e4 += 256) {
      int o = e4 >> 3, c4 = (e4 & 7)*4;
      float4 v = *reinterpret_cast<const float4*>(w + o*128 + ck*32 + c4);
      wt[o*33 + c4]   = v.x; wt[o*33 + c4+1] = v.y;
      wt[o*33 + c4+2] = v.z; wt[o*33 + c4+3] = v.w;
    }
    __syncthreads();
    for (int c = 0; c < 32; ++c) {
      float xv[8];
      #pragma unroll
      for (int j = 0; j < 8; ++j) xv[j] = xs[c*128 + pg*8 + j];
      #pragma unroll
      for (int i = 0; i < 4; ++i) {
        float wv = wt[(og + 16*i)*33 + c];
        #pragma unroll
        for (int j = 0; j < 8; ++j) acc[i][j] = fmaf(wv, xv[j], acc[i][j]);
      }
    }
  }
  float* Ab = A + (size_t)n*64*SP + rem;
  #pragma unroll
  for (int i = 0; i < 4; ++i) {
    const int o = og + 16*i;
    float s1 = 0.f, s2 = 0.f;
    #pragma unroll
    for (int j = 0; j < 8; ++j) { float v = acc[i][j]; s1 += v; s2 += v*v; }
    float4 a = make_float4(acc[i][0], acc[i][1], acc[i][2], acc[i][3]);
    float4 b = make_float4(acc[i][4], acc[i][5], acc[i][6], acc[i][7]);
    *reinterpret_cast<float4*>(Ab + (size_t)o*SP + pg*8)     = a;
    *reinterpret_cast<float4*>(Ab + (size_t)o*SP + pg*8 + 4) = b;
    atomicAdd(&ssum[o], s1);
    atomicAdd(&ssq[o], s2);
  }
  __syncthreads();
  if (t < 64) { atomicAdd(&st[t], ssum[t]); atomicAdd(&st[64+t], ssq[t]); }
}

// ---------------- transpose A[c][s][h][w] -> At[c][s][w][h] (dir 0) ----------------
__global__ void __launch_bounds__(256) kern_tr(
    const float* __restrict__ A, float* __restrict__ At)
{
  __shared__ float tile[56*57];
  const size_t base = (size_t)blockIdx.x*3136;
  for (int e4 = threadIdx.x; e4 < 784; e4 += 256) {
    int e = e4*4, h = e/56, w = e%56;
    float4 v = *reinterpret_cast<const float4*>(A + base + e);
    tile[w*57+h] = v.x; tile[(w+1)*57+h] = v.y;
    tile[(w+2)*57+h] = v.z; tile[(w+3)*57+h] = v.w;
  }
  __syncthreads();
  for (int e4 = threadIdx.x; e4 < 784; e4 += 256) {
    int e = e4*4, w = e/56, h = e%56;
    float4 v = make_float4(tile[w*57+h], tile[w*57+h+1], tile[w*57+h+2], tile[w*57+h+3]);
    *reinterpret_cast<float4*>(At + base + e) = v;
  }
}

// ---------------- transpose A[c][s][hw] -> At2[c][hw][s] (dir 2) ----------------
__global__ void __launch_bounds__(256) kern_tr2(
    const float* __restrict__ A, float* __restrict__ At2)
{
  __shared__ float tile[16*785];
  const int bid = blockIdx.x;                 // 128 slices * 4 chunks = 512
  const int slice = bid >> 2, hw0 = (bid & 3)*784;
  const float* Asrc = A + (size_t)slice*SP + hw0;
  for (int e4 = threadIdx.x; e4 < 3136; e4 += 256) {
    int s = e4/196, h4 = (e4%196)*4;
    float4 v = *reinterpret_cast<const float4*>(Asrc + (size_t)s*3136 + h4);
    tile[s*785 + h4]   = v.x; tile[s*785 + h4+1] = v.y;
    tile[s*785 + h4+2] = v.z; tile[s*785 + h4+3] = v.w;
  }
  __syncthreads();
  float* dst = At2 + ((size_t)slice*3136 + hw0)*16;
  for (int hw = threadIdx.x; hw < 784; hw += 256) {
    #pragma unroll
    for (int sq = 0; sq < 4; ++sq) {
      float4 v = make_float4(tile[(4*sq)*785 + hw], tile[(4*sq+1)*785 + hw],
                             tile[(4*sq+2)*785 + hw], tile[(4*sq+3)*785 + hw]);
      *reinterpret_cast<float4*>(dst + (size_t)hw*16 + sq*4) = v;
    }
  }
}

// ---------------- up-projection 64->128 (+relu) + bn2 stats (128-pos tile) ----------------
__global__ void __launch_bounds__(256) kern_up(
    const float* __restrict__ A, const float* __restrict__ w,
    float* __restrict__ U, float* __restrict__ st)
{
  __shared__ float xs[32*128];      // 16 KB
  __shared__ float wt[128*33];      // 16.9 KB
  __shared__ float ssum[128], ssq[128];
  const int t = threadIdx.x;
  if (t < 128) { ssum[t]=0.f; ssq[t]=0.f; }
  const int p0 = blockIdx.x*128;              // 784 blocks
  const int n = p0/SP, rem = p0%SP;
  const float* Ab = A + (size_t)n*64*SP + rem;
  const int og = t & 31, pg = t >> 5;         // o = og + 32*i, p = pg*16 + j
  float acc[4][16] = {};
  for (int ck = 0; ck < 2; ++ck) {
    __syncthreads();
    for (int e4 = t; e4 < 32*32; e4 += 256) {
      int c = e4 >> 5, p4 = (e4 & 31)*4;
      float4 v = *reinterpret_cast<const float4*>(Ab + (size_t)(ck*32+c)*SP + p4);
      v.x = fmaxf(v.x, 0.f); v.y = fmaxf(v.y, 0.f); v.z = fmaxf(v.z, 0.f); v.w = fmaxf(v.w, 0.f);
      *reinterpret_cast<float4*>(&xs[c*128 + p4]) = v;
    }
    for (int e4 = t; e4 < 128*8; e4 += 256) {
      int o = e4 >> 3, c4 = (e4 & 7)*4;
      float4 v = *reinterpret_cast<const float4*>(w + o*64 + ck*32 + c4);
      wt[o*33 + c4]   = v.x; wt[o*33 + c4+1] = v.y;
      wt[o*33 + c4+2] = v.z; wt[o*33 + c4+3] = v.w;
    }
    __syncthreads();
    for (int c = 0; c < 32; ++c) {
      float xv[16];
      #pragma unroll
      for (int j = 0; j < 16; ++j) xv[j] = xs[c*128 + pg*16 + j];
      #pragma unroll
      for (int i = 0; i < 4; ++i) {
        float wv = wt[(og + 32*i)*33 + c];
        #pragma unroll
        for (int j = 0; j < 16; ++j) acc[i][j] = fmaf(wv, xv[j], acc[i][j]);
      }
    }
  }
  float* Ub = U + (size_t)n*128*SP + rem;
  #pragma unroll
  for (int i = 0; i < 4; ++i) {
    const int o = og + 32*i;
    float s1=0.f, s2=0.f;
    #pragma unroll
    for (int j = 0; j < 16; ++j) { float v = acc[i][j]; s1 += v; s2 += v*v; }
    #pragma unroll
    for (int jq = 0; jq < 4; ++jq) {
      float4 a = make_float4(acc[i][jq*4],acc[i][jq*4+1],acc[i][jq*4+2],acc[i][jq*4+3]);
      *reinterpret_cast<float4*>(Ub + (size_t)o*SP + pg*16 + jq*4) = a;
    }
    atomicAdd(&ssum[o], s1); atomicAdd(&ssq[o], s2);
  }
  __syncthreads();
  if (t < 128) { atomicAdd(&st[t], ssum[t]); atomicAdd(&st[128+t], ssq[t]); }
}

// ---------------- qkv dirs 0/1: 2 adjacent q per block ----------------
template<bool FIRST>
__global__ void __launch_bounds__(256) kern_qkv(
    const float* __restrict__ src, const float* __restrict__ w,
    const float* __restrict__ st1, const float* __restrict__ g1,
    const float* __restrict__ b1,
    float* __restrict__ Bq, float* __restrict__ st)
{
  __shared__ float xs[32*112];
  __shared__ float wt[128*33];
  __shared__ float ssum[128], ssq[128];
  __shared__ float sc1s[64], sh1s[64];
  const int t = threadIdx.x;
  if (t < 128) { ssum[t]=0.f; ssq[t]=0.f; }
  if (FIRST && t < 64) {
    float mean = st1[t]*INVP;
    float var  = st1[64+t]*INVP - mean*mean;
    float sc   = g1[t]*rsqrtf(var + EPSV);
    sc1s[t] = sc; sh1s[t] = b1[t] - mean*sc;
  }
  const int b2 = blockIdx.x;                       // 896
  const int n = b2/448, r = b2%448, s = r/28, q0 = (r%28)*2;
  const size_t base = (size_t)n*64*SP + s*3136 + q0*56;
  const int og = t & 31, jg = t >> 5;
  float acc[4][14] = {};
  for (int ck = 0; ck < 2; ++ck) {
    __syncthreads();
    for (int e4 = t; e4 < 32*28; e4 += 256) {
      int c = e4/28, j4 = (e4%28)*4;
      float4 v = *reinterpret_cast<const float4*>(src + base + (size_t)(ck*32+c)*SP + j4);
      if (FIRST) {
        float sc = sc1s[ck*32+c], sh = sh1s[ck*32+c];
        v.x = fmaxf(fmaf(v.x, sc, sh), 0.f); v.y = fmaxf(fmaf(v.y, sc, sh), 0.f);
        v.z = fmaxf(fmaf(v.z, sc, sh), 0.f); v.w = fmaxf(fmaf(v.w, sc, sh), 0.f);
      }
      xs[c*112 + j4]   = v.x; xs[c*112 + j4+1] = v.y;
      xs[c*112 + j4+2] = v.z; xs[c*112 + j4+3] = v.w;
    }
    for (int e4 = t; e4 < 128*8; e4 += 256) {
      int o = e4 >> 3, c4 = (e4 & 7)*4;
      float4 v = *reinterpret_cast<const float4*>(w + o*64 + ck*32 + c4);
      wt[o*33 + c4]   = v.x; wt[o*33 + c4+1] = v.y;
      wt[o*33 + c4+2] = v.z; wt[o*33 + c4+3] = v.w;
    }
    __syncthreads();
    for (int c = 0; c < 32; ++c) {
      float xv[14];
      #pragma unroll
      for (int j = 0; j < 14; ++j) xv[j] = xs[c*112 + jg*14 + j];
      #pragma unroll
      for (int i = 0; i < 4; ++i) {
        float wv = wt[(og + 32*i)*33 + c];
        #pragma unroll
        for (int j = 0; j < 14; ++j) acc[i][j] = fmaf(wv, xv[j], acc[i][j]);
      }
    }
  }
  const int bo = (jg >= 4);
  const int colbase = jg*14 - bo*56;
  float* ob = Bq + ((size_t)(n*896 + s*56 + q0) + bo)*7168;   // 128*56 per b
  #pragma unroll
  for (int i = 0; i < 4; ++i) {
    const int o = og + 32*i;
    float s1=0.f, s2=0.f;
    #pragma unroll
    for (int j = 0; j < 14; ++j) {
      float v = acc[i][j];
      ob[o*56 + colbase + j] = v;
      s1 += v; s2 += v*v;
    }
    atomicAdd(&ssum[o], s1); atomicAdd(&ssq[o], s2);
  }
  __syncthreads();
  if (t < 128) { atomicAdd(&st[t], ssum[t]); atomicAdd(&st[128+t], ssq[t]); }
}

// ---------------- qkv dir 2 (seq): 8-w tile, dense reads of At2 ----------------
__global__ void __launch_bounds__(256) kern_qkv2(
    const float* __restrict__ At2, const float* __restrict__ w,
    float* __restrict__ Bq, float* __restrict__ st)
{
  __shared__ float xs[32*128];
  __shared__ float wt[128*33];
  __shared__ float ssum[128], ssq[128];
  const int t = threadIdx.x;
  if (t < 128) { ssum[t]=0.f; ssq[t]=0.f; }
  const int b = blockIdx.x;                       // 784
  const int n = b/392, r = b%392, y = r/7, w8 = (r%7)*8;
  const int og = t & 31, cg = t >> 5;
  float acc[4][16] = {};
  for (int ck = 0; ck < 2; ++ck) {
    __syncthreads();
    for (int e4 = t; e4 < 32*32; e4 += 256) {
      int c = e4 >> 5, rr = e4 & 31, wl = rr >> 2, s4 = (rr & 3)*4;
      float4 v = *reinterpret_cast<const float4*>(
          At2 + (((size_t)(n*64 + ck*32 + c)*3136) + y*56 + w8 + wl)*16 + s4);
      *reinterpret_cast<float4*>(&xs[c*128 + wl*16 + s4]) = v;
    }
    for (int e4 = t; e4 < 128*8; e4 += 256) {
      int o = e4 >> 3, c4 = (e4 & 7)*4;
      float4 v = *reinterpret_cast<const float4*>(w + o*64 + ck*32 + c4);
      wt[o*33 + c4]   = v.x; wt[o*33 + c4+1] = v.y;
      wt[o*33 + c4+2] = v.z; wt[o*33 + c4+3] = v.w;
    }
    __syncthreads();
    for (int c = 0; c < 32; ++c) {
      float xv[16];
      #pragma unroll
      for (int j = 0; j < 16; ++j) xv[j] = xs[c*128 + cg*16 + j];
      #pragma unroll
      for (int i = 0; i < 4; ++i) {
        float wv = wt[(og + 32*i)*33 + c];
        #pragma unroll
        for (int j = 0; j < 16; ++j) acc[i][j] = fmaf(wv, xv[j], acc[i][j]);
      }
    }
  }
  const size_t b0 = (size_t)n*3136 + (size_t)y*56 + w8;
  #pragma unroll
  for (int i = 0; i < 4; ++i) {
    const int o = og + 32*i;
    float s1=0.f, s2=0.f;
    #pragma unroll
    for (int j = 0; j < 16; ++j) {
      int col = cg*16 + j, wl = col >> 4, s = col & 15;
      float v = acc[i][j];
      Bq[(b0 + wl)*2048 + o*16 + s] = v;
      s1 += v; s2 += v*v;
    }
    atomicAdd(&ssum[o], s1); atomicAdd(&ssq[o], s2);
  }
  __syncthreads();
  if (t < 128) { atomicAdd(&st[t], ssum[t]); atomicAdd(&st[128+t], ssq[t]); }
}

// ---------------- fused partial reduction + BN finalize ----------------
__global__ void __launch_bounds__(256) kern_redfin(
    const float* __restrict__ part, const float* __restrict__ g,
    const float* __restrict__ b, float* __restrict__ scsh,
    int nb, int nch, float invc)
{
  const int ch = blockIdx.x;
  const int t = threadIdx.x;
  float s1 = 0.f, s2 = 0.f;
  for (int i = t; i < nb; i += 256) {
    s1 += part[(size_t)i*2*nch + ch];
    s2 += part[(size_t)i*2*nch + nch + ch];
  }
  #pragma unroll
  for (int off = 32; off >= 1; off >>= 1) { s1 += __shfl_xor(s1, off); s2 += __shfl_xor(s2, off); }
  __shared__ float r1[4], r2[4];
  if ((t & 63) == 0) { r1[t>>6] = s1; r2[t>>6] = s2; }
  __syncthreads();
  if (t == 0) {
    float S1 = r1[0]+r1[1]+r1[2]+r1[3], S2 = r2[0]+r2[1]+r2[2]+r2[3];
    float mean = S1*invc, var = S2*invc - mean*mean;
    float sc = g[ch]*rsqrtf(var + EPSV);
    scsh[ch] = sc;
    scsh[nch + ch] = b[ch] - mean*sc;
  }
}

// ---------------- scores pass 1 (folds bnq finalize from raw sums) ----------------
template<int H>
__global__ void __launch_bounds__(256) kern_pass1(
    const float* __restrict__ Bq, const float* __restrict__ stq,
    const float* __restrict__ gq, const float* __restrict__ bq,
    float* __restrict__ part)
{
  constexpr int PW = (H==16) ? 4 : 1;
  const int t = threadIdx.x;
  const int wave = t >> 6, lane = t & 63;
  const int sub = (PW==1) ? 0 : (lane >> 4);
  const int i = (PW==1) ? lane : (lane & 15);
  __shared__ float kls[4][4*H*PW];
  __shared__ float bs[16];
  __shared__ float qscs[128], qshs[128];
  if (t < 16) bs[t] = 0.f;
  if (t < 128) {
    float mean = stq[t]*INVP;
    float var  = stq[128+t]*INVP - mean*mean;
    float sc   = gq[t]*rsqrtf(var + EPSV);
    qscs[t] = sc; qshs[t] = bq[t] - mean*sc;
  }
  __syncthreads();
  float* klw = kls[wave];
  const int pair0 = (blockIdx.x*4 + wave)*PW;
  for (int e = lane; e < 4*H*PW; e += 64) {
    int sp = e / (4*H), r = e % (4*H);
    int c = r / H, j = r % H;
    int pr = pair0 + sp, bb = pr >> 3, g = pr & 7;
    int o = g*16 + 4 + c;
    klw[e] = fmaf(Bq[((size_t)bb*128 + o)*H + j], qscs[o], qshs[o]);
  }
  __syncthreads();
  const int pr = pair0 + sub, bb = pr >> 3, g = pr & 7;
  const float* kp = klw + sub*4*H;
  const bool act = (i < H);
  float q[4];
  #pragma unroll
  for (int c = 0; c < 4; ++c) {
    int o = g*16 + c;
    q[c] = act ? fmaf(Bq[((size_t)bb*128 + o)*H + i], qscs[o], qshs[o]) : 0.f;
  }
  float s1 = 0.f, s2 = 0.f;
  #pragma unroll
  for (int j = 0; j < H; ++j) {
    float s = q[0]*kp[j] + q[1]*kp[H+j] + q[2]*kp[2*H+j] + q[3]*kp[3*H+j];
    s1 += s; s2 += s*s;
  }
  #pragma unroll
  for (int off = (PW==1?32:8); off >= 1; off >>= 1) {
    s1 += __shfl_xor(s1, off);
    s2 += __shfl_xor(s2, off);
  }
  if ((lane & (PW==1?63:15)) == 0) { atomicAdd(&bs[g], s1); atomicAdd(&bs[8+g], s2); }
  __syncthreads();
  if (t < 16) part[(size_t)blockIdx.x*16 + t] = bs[t];
}

// ---------------- scores pass 2: softmax with max, register-cached scores ----------------
template<int H>
__global__ void __launch_bounds__(256) kern_attn(
    const float* __restrict__ Bq, const float* __restrict__ stq,
    const float* __restrict__ gq, const float* __restrict__ bq,
    const float* __restrict__ ssc,
    float* __restrict__ C, float* __restrict__ part)
{
  constexpr int PW = (H==16) ? 4 : 1;
  const int t = threadIdx.x;
  const int wave = t >> 6, lane = t & 63;
  const int sub = (PW==1) ? 0 : (lane >> 4);
  const int i = (PW==1) ? lane : (lane & 15);
  __shared__ float kv[4][12*H*PW];
  __shared__ float bsum[64], bsq[64];
  __shared__ float qscs[128], qshs[128];
  if (t < 64) { bsum[t] = 0.f; bsq[t] = 0.f; }
  if (t < 128) {
    float mean = stq[t]*INVP;
    float var  = stq[128+t]*INVP - mean*mean;
    float sc   = gq[t]*rsqrtf(var + EPSV);
    qscs[t] = sc; qshs[t] = bq[t] - mean*sc;
  }
  __syncthreads();
  float* kvw = kv[wave];
  const int pair0 = (blockIdx.x*4 + wave)*PW;
  for (int e = lane; e < 12*H*PW; e += 64) {
    int sp = e / (12*H), r = e % (12*H);
    int c = r / H, j = r % H;
    int pr = pair0 + sp, bb = pr >> 3, g = pr & 7;
    int o = g*16 + 4 + c;
    kvw[e] = fmaf(Bq[((size_t)bb*128 + o)*H + j], qscs[o], qshs[o]);
  }
  __syncthreads();
  const int pr = pair0 + sub, bb = pr >> 3, g = pr & 7;
  const float* kp = kvw + sub*12*H;
  const bool act = (i < H);
  const float As = ssc[g];   // bns shift cancels in softmax over j; hoist As into q
  float q[4];
  #pragma unroll
  for (int c = 0; c < 4; ++c) {
    int o = g*16 + c;
    q[c] = act ? fmaf(Bq[((size_t)bb*128 + o)*H + i], qscs[o], qshs[o]) * As : 0.f;
  }
  float den = 0.f;
  float acc[8] = {};
  // register-cached scores: compute dot once, max from cache, exp from cache
  float tv[H];
  #pragma unroll
  for (int j = 0; j < H; ++j)
    tv[j] = q[0]*kp[j] + q[1]*kp[H+j] + q[2]*kp[2*H+j] + q[3]*kp[3*H+j];
  float m = tv[0];
  #pragma unroll
  for (int j = 1; j < H; ++j) m = fmaxf(m, tv[j]);
  #pragma unroll
  for (int j = 0; j < H; ++j) {
    float e = __expf(tv[j] - m);
    den += e;
    #pragma unroll
    for (int c = 0; c < 8; ++c) acc[c] = fmaf(e, kp[(4+c)*H + j], acc[c]);
  }
  const float inv = 1.f/den;
  #pragma unroll
  for (int c = 0; c < 8; ++c) {
    float vv = act ? acc[c]*inv : 0.f;
    if (act) C[((size_t)bb*64 + g*8 + c)*H + i] = vv;
    float s1 = vv, s2 = vv*vv;
    #pragma unroll
    for (int off = (PW==1?32:8); off >= 1; off >>= 1) {
      s1 += __shfl_xor(s1, off);
      s2 += __shfl_xor(s2, off);
    }
    if ((lane & (PW==1?63:15)) == 0) { atomicAdd(&bsum[g*8+c], s1); atomicAdd(&bsq[g*8+c], s2); }
  }
  __syncthreads();
  if (t < 64) {
    part[(size_t)blockIdx.x*128 + t]      = bsum[t];
    part[(size_t)blockIdx.x*128 + 64 + t] = bsq[t];
  }
}

// ---------------- scatter sv back to canonical layout, bno normalize ----------------
__global__ void __launch_bounds__(256) kern_scat0(
    const float* __restrict__ C, const float* __restrict__ osc,
    const float* __restrict__ osh, float* __restrict__ A)
{
  __shared__ float tile[56*57];
  const int bid = blockIdx.x;
  const int c = bid & 63, s = (bid >> 6) & 15, n = bid >> 10;
  const float sc = osc[c], sh = osh[c];
  const size_t cb = ((size_t)(n*16+s)*56)*3584 + c*56;
  for (int e = threadIdx.x; e < 3136; e += 256) {
    int w = e/56, h = e%56;
    tile[w*57+h] = C[cb + (size_t)w*3584 + h];
  }
  __syncthreads();
  const size_t ab = ((size_t)(n*64+c)*16+s)*3136;
  for (int e = threadIdx.x; e < 3136; e += 256) {
    int h = e/56, w = e%56;
    A[ab + e] = fmaf(tile[w*57+h], sc, sh);
  }
}

__global__ void __launch_bounds__(256) kern_scat1(
    const float* __restrict__ C, const float* __restrict__ osc,
    const float* __restrict__ osh, float* __restrict__ A)
{
  const int e4 = blockIdx.x*256 + threadIdx.x;
  if (e4 >= 1792*64*14) return;
  const int w4 = (e4 % 14)*4, c = (e4/14) & 63, b = e4 / (14*64);
  const int n = b/896, r = b%896, s = r/56, y = r%56;
  const float sc = osc[c], sh = osh[c];
  float4 v = *reinterpret_cast<const float4*>(C + ((size_t)b*64 + c)*56 + w4);
  v.x = fmaf(v.x, sc, sh); v.y = fmaf(v.y, sc, sh);
  v.z = fmaf(v.z, sc, sh); v.w = fmaf(v.w, sc, sh);
  *reinterpret_cast<float4*>(A + ((size_t)(n*64+c)*16+s)*3136 + y*56 + w4) = v;
}

__global__ void __launch_bounds__(256) kern_scat2(
    const float* __restrict__ C, const float* __restrict__ osc,
    const float* __restrict__ osh, float* __restrict__ A)
{
  __shared__ float tile[56*17];
  const int bid = blockIdx.x;
  const int y = bid % 56, c = (bid/56) & 63, n = bid / 3584;
  const float sc = osc[c], sh = osh[c];
  const size_t cb = ((size_t)(n*56+y)*56)*1024 + c*16;
  for (int e = threadIdx.x; e < 896; e += 256) {
    int w = e >> 4, s = e & 15;
    tile[w*17+s] = C[cb + (size_t)w*1024 + s];
  }
  __syncthreads();
  const size_t ab = (size_t)(n*64+c)*16*3136 + y*56;
  for (int e = threadIdx.x; e < 896; e += 256) {
    int s = e/56, w = e%56;
    A[ab + (size_t)s*3136 + w] = fmaf(tile[w*17+s], sc, sh);
  }
}

// ---------------- final: relu(bn2(U) + identity), bn2 finalize folded ----------------
__global__ void __launch_bounds__(256) kern_final(
    float* __restrict__ U, const float* __restrict__ x,
    const float* __restrict__ st2, const float* __restrict__ g2,
    const float* __restrict__ b2, float* __restrict__ out)
{
  __shared__ float scs[128], shs[128];
  const int t = threadIdx.x;
  if (t < 128) {
    float mean = st2[t]*INVP;
    float var  = st2[128+t]*INVP - mean*mean;
    float sc   = g2[t]*rsqrtf(var + EPSV);
    scs[t] = sc; shs[t] = b2[t] - mean*sc;
  }
  __syncthreads();
  const int idx = blockIdx.x*256 + t;
  if (idx >= P*128/4) return;
  const int e = idx*4;
  const int o = (e / SP) & 127;
  float4 u  = *reinterpret_cast<const float4*>(U + e);
  float4 xv = *reinterpret_cast<const float4*>(x + e);
  const float s = scs[o], h = shs[o];
  float4 r;
  r.x = fmaxf(fmaf(u.x, s, h) + xv.x, 0.f);
  r.y = fmaxf(fmaf(u.y, s, h) + xv.y, 0.f);
  r.z = fmaxf(fmaf(u.z, s, h) + xv.z, 0.f);
  r.w = fmaxf(fmaf(u.w, s, h) + xv.w, 0.f);
  *reinterpret_cast<float4*>(out + e) = r;
}

extern "C" void kernel_launch(void* const* d_in, const int* in_sizes, int n_in,
                              void* d_out, int out_size, void* d_ws, size_t ws_size,
                              hipStream_t stream)
{
  const float* x    = (const float*)d_in[0];
  const float* cdw  = (const float*)d_in[1];
  const float* bn1g = (const float*)d_in[2];
  const float* bn1b = (const float*)d_in[3];
  const float* qkvw = (const float*)d_in[4];
  const float* bnqg = (const float*)d_in[5];
  const float* bnqb = (const float*)d_in[6];
  const float* bnsg = (const float*)d_in[7];
  const float* bnsb = (const float*)d_in[8];
  const float* bnog = (const float*)d_in[9];
  const float* bnob = (const float*)d_in[10];
  const float* cuw  = (const float*)d_in[11];
  const float* bn2g = (const float*)d_in[12];
  const float* bn2b = (const float*)d_in[13];
  float* out = (float*)d_out;
  float* ws  = (float*)d_ws;

  float* A   = ws + OFF_A;
  float* C   = ws + OFF_C;
  float* st  = ws + OFF_ST;
  float* Pp1 = ws + OFF_P1;
  float* Pp2 = ws + OFF_P2;
  float* Bq  = out;

  hipMemsetAsync(st, 0, 4096*sizeof(float), stream);

  // stage A: down-proj (bn1 raw sums into st[0..127])
  kern_down<<<P/128, 256, 0, stream>>>(x, cdw, A, st);

  // direction 0: 'x'
  {
    float* stq = st + 256; float* sts = stq + 512; float* sto = stq + 544;
    kern_tr<<<2048, 256, 0, stream>>>(A, C);
    kern_qkv<true><<<896, 256, 0, stream>>>(C, qkvw, st, bn1g, bn1b, Bq, stq);
    kern_pass1<56><<<3584, 256, 0, stream>>>(Bq, stq, bnqg, bnqb, Pp1);
    kern_redfin<<<8, 256, 0, stream>>>(Pp1, bnsg, bnsb, sts, 3584, 8, 1.f/5619712.f);
    kern_attn<56><<<3584, 256, 0, stream>>>(Bq, stq, bnqg, bnqb, sts, C, Pp2);
    kern_redfin<<<64, 256, 0, stream>>>(Pp2, bnog, bnob, sto, 3584, 64, INVP);
    kern_scat0<<<2048, 256, 0, stream>>>(C, sto, sto+64, A);
  }
  // direction 1: 'y'
  {
    float* stq = st + 256 + 1024; float* sts = stq + 512; float* sto = stq + 544;
    kern_qkv<false><<<896, 256, 0, stream>>>(A, qkvw+8192, st, bn1g, bn1b, Bq, stq);
    kern_pass1<56><<<3584, 256, 0, stream>>>(Bq, stq, bnqg+128, bnqb+128, Pp1);
    kern_redfin<<<8, 256, 0, stream>>>(Pp1, bnsg+8, bnsb+8, sts, 3584, 8, 1.f/5619712.f);
    kern_attn<56><<<3584, 256, 0, stream>>>(Bq, stq, bnqg+128, bnqb+128, sts, C, Pp2);
    kern_redfin<<<64, 256, 0, stream>>>(Pp2, bnog+64, bnob+64, sto, 3584, 64, INVP);
    kern_scat1<<<6272, 256, 0, stream>>>(C, sto, sto+64, A);
  }
  // direction 2: 'seq'
  {
    float* stq = st + 256 + 2048; float* sts = stq + 512; float* sto = stq + 544;
    kern_tr2<<<512, 256, 0, stream>>>(A, C);
    kern_qkv2<<<784, 256, 0, stream>>>(C, qkvw+16384, Bq, stq);
    kern_pass1<16><<<3136, 256, 0, stream>>>(Bq, stq, bnqg+256, bnqb+256, Pp1);
    kern_redfin<<<8, 256, 0, stream>>>(Pp1, bnsg+16, bnsb+16, sts, 3136, 8, 1.f/1605632.f);
    kern_attn<16><<<3136, 256, 0, stream>>>(Bq, stq, bnqg+256, bnqb+256, sts, C, Pp2);
    kern_redfin<<<64, 256, 0, stream>>>(Pp2, bnog+128, bnob+128, sto, 3136, 64, INVP);
    kern_scat2<<<7168, 256, 0, stream>>>(C, sto, sto+64, A);
  }

  // stage B: relu -> up-proj (bn2 raw sums) -> residual + relu (bn2 folded)
  float* st2 = st + 3328;
  kern_up<<<P/128, 256, 0, stream>>>(A, cuw, Bq, st2);
  kern_final<<<P*128/4/256, 256, 0, stream>>>(Bq, x, st2, bn2g, bn2b, out);
}

// Round 22
// 566.354 us; speedup vs baseline: 1.3705x; 1.3705x over previous
//
#include <hip/hip_runtime.h>

constexpr int SP = 16*56*56;      // 50176 spatial per batch
constexpr int P  = 2*SP;          // 100352 positions
constexpr float EPSV = 1e-5f;
constexpr float INVP = 1.f/100352.f;

constexpr size_t SZ_A   = (size_t)2*64*SP;   // 6422528
constexpr size_t OFF_A  = 0;
constexpr size_t OFF_C  = SZ_A;
constexpr size_t OFF_ST = OFF_C + SZ_A;      // 4096 floats of stats
constexpr size_t OFF_P1 = 0;        // pass1 partials (inside dead A region)
constexpr size_t OFF_P2 = 65536;    // attn partials (inside dead A region)

// ---------------- down-projection 128->64 + bn1 stats (128-pos tile, 4 c-chunks of 32) ----------------
__global__ void __launch_bounds__(256) kern_down(
    const float* __restrict__ x, const float* __restrict__ w,
    float* __restrict__ A, float* __restrict__ st)
{
  __shared__ float xs[32*128];      // [c-local][p]  16 KB
  __shared__ float wt[64*33];       // [o][c-local]  8.25 KB
  __shared__ float ssum[64], ssq[64];
  const int t = threadIdx.x;
  if (t < 64) { ssum[t] = 0.f; ssq[t] = 0.f; }
  const int p0 = blockIdx.x * 128;            // 784 blocks
  const int n = p0 / SP, rem = p0 % SP;
  const float* xb = x + (size_t)n*128*SP + rem;
  const int og = t & 15, pg = t >> 4;         // o = og + 16*i, p = pg*8 + j
  float acc[4][8] = {};
  for (int ck = 0; ck < 4; ++ck) {
    __syncthreads();
    for (int e4 = t; e4 < 32*32; e4 += 256) {
      int c = e4 >> 5, p4 = (e4 & 31)*4;
      float4 v = *reinterpret_cast<const float4*>(xb + (size_t)(ck*32+c)*SP + p4);
      *reinterpret_cast<float4*>(&xs[c*128 + p4]) = v;
    }
    for (int e4 = t; e4 < 64*8; e4 += 256) {
      int o = e4 >> 3, c4 = (e4 & 7)*4;
      float4 v = *reinterpret_cast<const float4*>(w + o*128 + ck*32 + c4);
      wt[o*33 + c4]   = v.x; wt[o*33 + c4+1] = v.y;
      wt[o*33 + c4+2] = v.z; wt[o*33 + c4+3] = v.w;
    }
    __syncthreads();
    for (int c = 0; c < 32; ++c) {
      float xv[8];
      #pragma unroll
      for (int j = 0; j < 8; ++j) xv[j] = xs[c*128 + pg*8 + j];
      #pragma unroll
      for (int i = 0; i < 4; ++i) {
        float wv = wt[(og + 16*i)*33 + c];
        #pragma unroll
        for (int j = 0; j < 8; ++j) acc[i][j] = fmaf(wv, xv[j], acc[i][j]);
      }
    }
  }
  float* Ab = A + (size_t)n*64*SP + rem;
  #pragma unroll
  for (int i = 0; i < 4; ++i) {
    const int o = og + 16*i;
    float s1 = 0.f, s2 = 0.f;
    #pragma unroll
    for (int j = 0; j < 8; ++j) { float v = acc[i][j]; s1 += v; s2 += v*v; }
    float4 a = make_float4(acc[i][0], acc[i][1], acc[i][2], acc[i][3]);
    float4 b = make_float4(acc[i][4], acc[i][5], acc[i][6], acc[i][7]);
    *reinterpret_cast<float4*>(Ab + (size_t)o*SP + pg*8)     = a;
    *reinterpret_cast<float4*>(Ab + (size_t)o*SP + pg*8 + 4) = b;
    atomicAdd(&ssum[o], s1);
    atomicAdd(&ssq[o], s2);
  }
  __syncthreads();
  if (t < 64) { atomicAdd(&st[t], ssum[t]); atomicAdd(&st[64+t], ssq[t]); }
}

// ---------------- transpose A[c][s][h][w] -> At[c][s][w][h] (dir 0) ----------------
__global__ void __launch_bounds__(256) kern_tr(
    const float* __restrict__ A, float* __restrict__ At)
{
  __shared__ float tile[56*57];
  const size_t base = (size_t)blockIdx.x*3136;
  for (int e4 = threadIdx.x; e4 < 784; e4 += 256) {
    int e = e4*4, h = e/56, w = e%56;
    float4 v = *reinterpret_cast<const float4*>(A + base + e);
    tile[w*57+h] = v.x; tile[(w+1)*57+h] = v.y;
    tile[(w+2)*57+h] = v.z; tile[(w+3)*57+h] = v.w;
  }
  __syncthreads();
  for (int e4 = threadIdx.x; e4 < 784; e4 += 256) {
    int e = e4*4, w = e/56, h = e%56;
    float4 v = make_float4(tile[w*57+h], tile[w*57+h+1], tile[w*57+h+2], tile[w*57+h+3]);
    *reinterpret_cast<float4*>(At + base + e) = v;
  }
}

// ---------------- transpose A[c][s][hw] -> At2[c][hw][s] (dir 2) ----------------
__global__ void __launch_bounds__(256) kern_tr2(
    const float* __restrict__ A, float* __restrict__ At2)
{
  __shared__ float tile[16*785];
  const int bid = blockIdx.x;                 // 128 slices * 4 chunks = 512
  const int slice = bid >> 2, hw0 = (bid & 3)*784;
  const float* Asrc = A + (size_t)slice*SP + hw0;
  for (int e4 = threadIdx.x; e4 < 3136; e4 += 256) {
    int s = e4/196, h4 = (e4%196)*4;
    float4 v = *reinterpret_cast<const float4*>(Asrc + (size_t)s*3136 + h4);
    tile[s*785 + h4]   = v.x; tile[s*785 + h4+1] = v.y;
    tile[s*785 + h4+2] = v.z; tile[s*785 + h4+3] = v.w;
  }
  __syncthreads();
  float* dst = At2 + ((size_t)slice*3136 + hw0)*16;
  for (int hw = threadIdx.x; hw < 784; hw += 256) {
    #pragma unroll
    for (int sq = 0; sq < 4; ++sq) {
      float4 v = make_float4(tile[(4*sq)*785 + hw], tile[(4*sq+1)*785 + hw],
                             tile[(4*sq+2)*785 + hw], tile[(4*sq+3)*785 + hw]);
      *reinterpret_cast<float4*>(dst + (size_t)hw*16 + sq*4) = v;
    }
  }
}

// ---------------- up-projection 64->128 (+relu) + bn2 stats (128-pos tile) ----------------
__global__ void __launch_bounds__(256) kern_up(
    const float* __restrict__ A, const float* __restrict__ w,
    float* __restrict__ U, float* __restrict__ st)
{
  __shared__ float xs[32*128];      // 16 KB
  __shared__ float wt[128*33];      // 16.9 KB
  __shared__ float ssum[128], ssq[128];
  const int t = threadIdx.x;
  if (t < 128) { ssum[t]=0.f; ssq[t]=0.f; }
  const int p0 = blockIdx.x*128;              // 784 blocks
  const int n = p0/SP, rem = p0%SP;
  const float* Ab = A + (size_t)n*64*SP + rem;
  const int og = t & 31, pg = t >> 5;         // o = og + 32*i, p = pg*16 + j
  float acc[4][16] = {};
  for (int ck = 0; ck < 2; ++ck) {
    __syncthreads();
    for (int e4 = t; e4 < 32*32; e4 += 256) {
      int c = e4 >> 5, p4 = (e4 & 31)*4;
      float4 v = *reinterpret_cast<const float4*>(Ab + (size_t)(ck*32+c)*SP + p4);
      v.x = fmaxf(v.x, 0.f); v.y = fmaxf(v.y, 0.f); v.z = fmaxf(v.z, 0.f); v.w = fmaxf(v.w, 0.f);
      *reinterpret_cast<float4*>(&xs[c*128 + p4]) = v;
    }
    for (int e4 = t; e4 < 128*8; e4 += 256) {
      int o = e4 >> 3, c4 = (e4 & 7)*4;
      float4 v = *reinterpret_cast<const float4*>(w + o*64 + ck*32 + c4);
      wt[o*33 + c4]   = v.x; wt[o*33 + c4+1] = v.y;
      wt[o*33 + c4+2] = v.z; wt[o*33 + c4+3] = v.w;
    }
    __syncthreads();
    for (int c = 0; c < 32; ++c) {
      float xv[16];
      #pragma unroll
      for (int j = 0; j < 16; ++j) xv[j] = xs[c*128 + pg*16 + j];
      #pragma unroll
      for (int i = 0; i < 4; ++i) {
        float wv = wt[(og + 32*i)*33 + c];
        #pragma unroll
        for (int j = 0; j < 16; ++j) acc[i][j] = fmaf(wv, xv[j], acc[i][j]);
      }
    }
  }
  float* Ub = U + (size_t)n*128*SP + rem;
  #pragma unroll
  for (int i = 0; i < 4; ++i) {
    const int o = og + 32*i;
    float s1=0.f, s2=0.f;
    #pragma unroll
    for (int j = 0; j < 16; ++j) { float v = acc[i][j]; s1 += v; s2 += v*v; }
    #pragma unroll
    for (int jq = 0; jq < 4; ++jq) {
      float4 a = make_float4(acc[i][jq*4],acc[i][jq*4+1],acc[i][jq*4+2],acc[i][jq*4+3]);
      *reinterpret_cast<float4*>(Ub + (size_t)o*SP + pg*16 + jq*4) = a;
    }
    atomicAdd(&ssum[o], s1); atomicAdd(&ssq[o], s2);
  }
  __syncthreads();
  if (t < 128) { atomicAdd(&st[t], ssum[t]); atomicAdd(&st[128+t], ssq[t]); }
}

// ---------------- qkv dirs 0/1: 2 adjacent q per block ----------------
template<bool FIRST>
__global__ void __launch_bounds__(256) kern_qkv(
    const float* __restrict__ src, const float* __restrict__ w,
    const float* __restrict__ st1, const float* __restrict__ g1,
    const float* __restrict__ b1,
    float* __restrict__ Bq, float* __restrict__ st)
{
  __shared__ float xs[32*112];
  __shared__ float wt[128*33];
  __shared__ float ssum[128], ssq[128];
  __shared__ float sc1s[64], sh1s[64];
  const int t = threadIdx.x;
  if (t < 128) { ssum[t]=0.f; ssq[t]=0.f; }
  if (FIRST && t < 64) {
    float mean = st1[t]*INVP;
    float var  = st1[64+t]*INVP - mean*mean;
    float sc   = g1[t]*rsqrtf(var + EPSV);
    sc1s[t] = sc; sh1s[t] = b1[t] - mean*sc;
  }
  const int b2 = blockIdx.x;                       // 896
  const int n = b2/448, r = b2%448, s = r/28, q0 = (r%28)*2;
  const size_t base = (size_t)n*64*SP + s*3136 + q0*56;
  const int og = t & 31, jg = t >> 5;
  float acc[4][14] = {};
  for (int ck = 0; ck < 2; ++ck) {
    __syncthreads();
    for (int e4 = t; e4 < 32*28; e4 += 256) {
      int c = e4/28, j4 = (e4%28)*4;
      float4 v = *reinterpret_cast<const float4*>(src + base + (size_t)(ck*32+c)*SP + j4);
      if (FIRST) {
        float sc = sc1s[ck*32+c], sh = sh1s[ck*32+c];
        v.x = fmaxf(fmaf(v.x, sc, sh), 0.f); v.y = fmaxf(fmaf(v.y, sc, sh), 0.f);
        v.z = fmaxf(fmaf(v.z, sc, sh), 0.f); v.w = fmaxf(fmaf(v.w, sc, sh), 0.f);
      }
      xs[c*112 + j4]   = v.x; xs[c*112 + j4+1] = v.y;
      xs[c*112 + j4+2] = v.z; xs[c*112 + j4+3] = v.w;
    }
    for (int e4 = t; e4 < 128*8; e4 += 256) {
      int o = e4 >> 3, c4 = (e4 & 7)*4;
      float4 v = *reinterpret_cast<const float4*>(w + o*64 + ck*32 + c4);
      wt[o*33 + c4]   = v.x; wt[o*33 + c4+1] = v.y;
      wt[o*33 + c4+2] = v.z; wt[o*33 + c4+3] = v.w;
    }
    __syncthreads();
    for (int c = 0; c < 32; ++c) {
      float xv[14];
      #pragma unroll
      for (int j = 0; j < 14; ++j) xv[j] = xs[c*112 + jg*14 + j];
      #pragma unroll
      for (int i = 0; i < 4; ++i) {
        float wv = wt[(og + 32*i)*33 + c];
        #pragma unroll
        for (int j = 0; j < 14; ++j) acc[i][j] = fmaf(wv, xv[j], acc[i][j]);
      }
    }
  }
  const int bo = (jg >= 4);
  const int colbase = jg*14 - bo*56;
  float* ob = Bq + ((size_t)(n*896 + s*56 + q0) + bo)*7168;   // 128*56 per b
  #pragma unroll
  for (int i = 0; i < 4; ++i) {
    const int o = og + 32*i;
    float s1=0.f, s2=0.f;
    #pragma unroll
    for (int j = 0; j < 14; ++j) {
      float v = acc[i][j];
      ob[o*56 + colbase + j] = v;
      s1 += v; s2 += v*v;
    }
    atomicAdd(&ssum[o], s1); atomicAdd(&ssq[o], s2);
  }
  __syncthreads();
  if (t < 128) { atomicAdd(&st[t], ssum[t]); atomicAdd(&st[128+t], ssq[t]); }
}

// ---------------- qkv dir 2 (seq): 8-w tile, dense reads of At2 ----------------
__global__ void __launch_bounds__(256) kern_qkv2(
    const float* __restrict__ At2, const float* __restrict__ w,
    float* __restrict__ Bq, float* __restrict__ st)
{
  __shared__ float xs[32*128];
  __shared__ float wt[128*33];
  __shared__ float ssum[128], ssq[128];
  const int t = threadIdx.x;
  if (t < 128) { ssum[t]=0.f; ssq[t]=0.f; }
  const int b = blockIdx.x;                       // 784
  const int n = b/392, r = b%392, y = r/7, w8 = (r%7)*8;
  const int og = t & 31, cg = t >> 5;
  float acc[4][16] = {};
  for (int ck = 0; ck < 2; ++ck) {
    __syncthreads();
    for (int e4 = t; e4 < 32*32; e4 += 256) {
      int c = e4 >> 5, rr = e4 & 31, wl = rr >> 2, s4 = (rr & 3)*4;
      float4 v = *reinterpret_cast<const float4*>(
          At2 + (((size_t)(n*64 + ck*32 + c)*3136) + y*56 + w8 + wl)*16 + s4);
      *reinterpret_cast<float4*>(&xs[c*128 + wl*16 + s4]) = v;
    }
    for (int e4 = t; e4 < 128*8; e4 += 256) {
      int o = e4 >> 3, c4 = (e4 & 7)*4;
      float4 v = *reinterpret_cast<const float4*>(w + o*64 + ck*32 + c4);
      wt[o*33 + c4]   = v.x; wt[o*33 + c4+1] = v.y;
      wt[o*33 + c4+2] = v.z; wt[o*33 + c4+3] = v.w;
    }
    __syncthreads();
    for (int c = 0; c < 32; ++c) {
      float xv[16];
      #pragma unroll
      for (int j = 0; j < 16; ++j) xv[j] = xs[c*128 + cg*16 + j];
      #pragma unroll
      for (int i = 0; i < 4; ++i) {
        float wv = wt[(og + 32*i)*33 + c];
        #pragma unroll
        for (int j = 0; j < 16; ++j) acc[i][j] = fmaf(wv, xv[j], acc[i][j]);
      }
    }
  }
  const size_t b0 = (size_t)n*3136 + (size_t)y*56 + w8;
  #pragma unroll
  for (int i = 0; i < 4; ++i) {
    const int o = og + 32*i;
    float s1=0.f, s2=0.f;
    #pragma unroll
    for (int j = 0; j < 16; ++j) {
      int col = cg*16 + j, wl = col >> 4, s = col & 15;
      float v = acc[i][j];
      Bq[(b0 + wl)*2048 + o*16 + s] = v;
      s1 += v; s2 += v*v;
    }
    atomicAdd(&ssum[o], s1); atomicAdd(&ssq[o], s2);
  }
  __syncthreads();
  if (t < 128) { atomicAdd(&st[t], ssum[t]); atomicAdd(&st[128+t], ssq[t]); }
}

// ---------------- fused partial reduction + BN finalize ----------------
__global__ void __launch_bounds__(256) kern_redfin(
    const float* __restrict__ part, const float* __restrict__ g,
    const float* __restrict__ b, float* __restrict__ scsh,
    int nb, int nch, float invc)
{
  const int ch = blockIdx.x;
  const int t = threadIdx.x;
  float s1 = 0.f, s2 = 0.f;
  for (int i = t; i < nb; i += 256) {
    s1 += part[(size_t)i*2*nch + ch];
    s2 += part[(size_t)i*2*nch + nch + ch];
  }
  #pragma unroll
  for (int off = 32; off >= 1; off >>= 1) { s1 += __shfl_xor(s1, off); s2 += __shfl_xor(s2, off); }
  __shared__ float r1[4], r2[4];
  if ((t & 63) == 0) { r1[t>>6] = s1; r2[t>>6] = s2; }
  __syncthreads();
  if (t == 0) {
    float S1 = r1[0]+r1[1]+r1[2]+r1[3], S2 = r2[0]+r2[1]+r2[2]+r2[3];
    float mean = S1*invc, var = S2*invc - mean*mean;
    float sc = g[ch]*rsqrtf(var + EPSV);
    scsh[ch] = sc;
    scsh[nch + ch] = b[ch] - mean*sc;
  }
}

// ---------------- scores pass 1 (folds bnq finalize from raw sums) ----------------
template<int H>
__global__ void __launch_bounds__(256) kern_pass1(
    const float* __restrict__ Bq, const float* __restrict__ stq,
    const float* __restrict__ gq, const float* __restrict__ bq,
    float* __restrict__ part)
{
  constexpr int PW = (H==16) ? 4 : 1;
  const int t = threadIdx.x;
  const int wave = t >> 6, lane = t & 63;
  const int sub = (PW==1) ? 0 : (lane >> 4);
  const int i = (PW==1) ? lane : (lane & 15);
  __shared__ float kls[4][4*H*PW];
  __shared__ float bs[16];
  __shared__ float qscs[128], qshs[128];
  if (t < 16) bs[t] = 0.f;
  if (t < 128) {
    float mean = stq[t]*INVP;
    float var  = stq[128+t]*INVP - mean*mean;
    float sc   = gq[t]*rsqrtf(var + EPSV);
    qscs[t] = sc; qshs[t] = bq[t] - mean*sc;
  }
  __syncthreads();
  float* klw = kls[wave];
  const int pair0 = (blockIdx.x*4 + wave)*PW;
  for (int e = lane; e < 4*H*PW; e += 64) {
    int sp = e / (4*H), r = e % (4*H);
    int c = r / H, j = r % H;
    int pr = pair0 + sp, bb = pr >> 3, g = pr & 7;
    int o = g*16 + 4 + c;
    klw[e] = fmaf(Bq[((size_t)bb*128 + o)*H + j], qscs[o], qshs[o]);
  }
  __syncthreads();
  const int pr = pair0 + sub, bb = pr >> 3, g = pr & 7;
  const float* kp = klw + sub*4*H;
  const bool act = (i < H);
  float q[4];
  #pragma unroll
  for (int c = 0; c < 4; ++c) {
    int o = g*16 + c;
    q[c] = act ? fmaf(Bq[((size_t)bb*128 + o)*H + i], qscs[o], qshs[o]) : 0.f;
  }
  float s1 = 0.f, s2 = 0.f;
  #pragma unroll
  for (int j = 0; j < H; ++j) {
    float s = q[0]*kp[j] + q[1]*kp[H+j] + q[2]*kp[2*H+j] + q[3]*kp[3*H+j];
    s1 += s; s2 += s*s;
  }
  #pragma unroll
  for (int off = (PW==1?32:8); off >= 1; off >>= 1) {
    s1 += __shfl_xor(s1, off);
    s2 += __shfl_xor(s2, off);
  }
  if ((lane & (PW==1?63:15)) == 0) { atomicAdd(&bs[g], s1); atomicAdd(&bs[8+g], s2); }
  __syncthreads();
  if (t < 16) part[(size_t)blockIdx.x*16 + t] = bs[t];
}

// ---------------- scores pass 2: softmax with max (two-sweep for H=56; reg-cached for H=16) ----------------
template<int H>
__global__ void __launch_bounds__(256) kern_attn(
    const float* __restrict__ Bq, const float* __restrict__ stq,
    const float* __restrict__ gq, const float* __restrict__ bq,
    const float* __restrict__ ssc,
    float* __restrict__ C, float* __restrict__ part)
{
  constexpr int PW = (H==16) ? 4 : 1;
  const int t = threadIdx.x;
  const int wave = t >> 6, lane = t & 63;
  const int sub = (PW==1) ? 0 : (lane >> 4);
  const int i = (PW==1) ? lane : (lane & 15);
  __shared__ float kv[4][12*H*PW];
  __shared__ float bsum[64], bsq[64];
  __shared__ float qscs[128], qshs[128];
  if (t < 64) { bsum[t] = 0.f; bsq[t] = 0.f; }
  if (t < 128) {
    float mean = stq[t]*INVP;
    float var  = stq[128+t]*INVP - mean*mean;
    float sc   = gq[t]*rsqrtf(var + EPSV);
    qscs[t] = sc; qshs[t] = bq[t] - mean*sc;
  }
  __syncthreads();
  float* kvw = kv[wave];
  const int pair0 = (blockIdx.x*4 + wave)*PW;
  for (int e = lane; e < 12*H*PW; e += 64) {
    int sp = e / (12*H), r = e % (12*H);
    int c = r / H, j = r % H;
    int pr = pair0 + sp, bb = pr >> 3, g = pr & 7;
    int o = g*16 + 4 + c;
    kvw[e] = fmaf(Bq[((size_t)bb*128 + o)*H + j], qscs[o], qshs[o]);
  }
  __syncthreads();
  const int pr = pair0 + sub, bb = pr >> 3, g = pr & 7;
  const float* kp = kvw + sub*12*H;
  const bool act = (i < H);
  float q[4];
  #pragma unroll
  for (int c = 0; c < 4; ++c) {
    int o = g*16 + c;
    q[c] = act ? fmaf(Bq[((size_t)bb*128 + o)*H + i], qscs[o], qshs[o]) : 0.f;
  }
  const float As = ssc[g];   // bns shift cancels in softmax over j
  float den = 0.f;
  float acc[8] = {};
  if constexpr (H == 16) {
    float tv[16];
    #pragma unroll
    for (int j = 0; j < 16; ++j)
      tv[j] = As * (q[0]*kp[j] + q[1]*kp[H+j] + q[2]*kp[2*H+j] + q[3]*kp[3*H+j]);
    float m = tv[0];
    #pragma unroll
    for (int j = 1; j < 16; ++j) m = fmaxf(m, tv[j]);
    #pragma unroll
    for (int j = 0; j < 16; ++j) {
      float e = __expf(tv[j] - m);
      den += e;
      #pragma unroll
      for (int c = 0; c < 8; ++c) acc[c] = fmaf(e, kp[(4+c)*H + j], acc[c]);
    }
  } else {
    float m = -3.4e38f;
    for (int j = 0; j < H; ++j) {
      float s = As * (q[0]*kp[j] + q[1]*kp[H+j] + q[2]*kp[2*H+j] + q[3]*kp[3*H+j]);
      m = fmaxf(m, s);
    }
    for (int j = 0; j < H; ++j) {
      float s = As * (q[0]*kp[j] + q[1]*kp[H+j] + q[2]*kp[2*H+j] + q[3]*kp[3*H+j]);
      float e = __expf(s - m);
      den += e;
      #pragma unroll
      for (int c = 0; c < 8; ++c) acc[c] = fmaf(e, kp[(4+c)*H + j], acc[c]);
    }
  }
  const float inv = 1.f/den;
  #pragma unroll
  for (int c = 0; c < 8; ++c) {
    float vv = act ? acc[c]*inv : 0.f;
    if (act) C[((size_t)bb*64 + g*8 + c)*H + i] = vv;
    float s1 = vv, s2 = vv*vv;
    #pragma unroll
    for (int off = (PW==1?32:8); off >= 1; off >>= 1) {
      s1 += __shfl_xor(s1, off);
      s2 += __shfl_xor(s2, off);
    }
    if ((lane & (PW==1?63:15)) == 0) { atomicAdd(&bsum[g*8+c], s1); atomicAdd(&bsq[g*8+c], s2); }
  }
  __syncthreads();
  if (t < 64) {
    part[(size_t)blockIdx.x*128 + t]      = bsum[t];
    part[(size_t)blockIdx.x*128 + 64 + t] = bsq[t];
  }
}

// ---------------- scatter sv back to canonical layout, bno normalize ----------------
__global__ void __launch_bounds__(256) kern_scat0(
    const float* __restrict__ C, const float* __restrict__ osc,
    const float* __restrict__ osh, float* __restrict__ A)
{
  __shared__ float tile[56*57];
  const int bid = blockIdx.x;
  const int c = bid & 63, s = (bid >> 6) & 15, n = bid >> 10;
  const float sc = osc[c], sh = osh[c];
  const size_t cb = ((size_t)(n*16+s)*56)*3584 + c*56;
  for (int e = threadIdx.x; e < 3136; e += 256) {
    int w = e/56, h = e%56;
    tile[w*57+h] = C[cb + (size_t)w*3584 + h];
  }
  __syncthreads();
  const size_t ab = ((size_t)(n*64+c)*16+s)*3136;
  for (int e = threadIdx.x; e < 3136; e += 256) {
    int h = e/56, w = e%56;
    A[ab + e] = fmaf(tile[w*57+h], sc, sh);
  }
}

__global__ void __launch_bounds__(256) kern_scat1(
    const float* __restrict__ C, const float* __restrict__ osc,
    const float* __restrict__ osh, float* __restrict__ A)
{
  const int e4 = blockIdx.x*256 + threadIdx.x;
  if (e4 >= 1792*64*14) return;
  const int w4 = (e4 % 14)*4, c = (e4/14) & 63, b = e4 / (14*64);
  const int n = b/896, r = b%896, s = r/56, y = r%56;
  const float sc = osc[c], sh = osh[c];
  float4 v = *reinterpret_cast<const float4*>(C + ((size_t)b*64 + c)*56 + w4);
  v.x = fmaf(v.x, sc, sh); v.y = fmaf(v.y, sc, sh);
  v.z = fmaf(v.z, sc, sh); v.w = fmaf(v.w, sc, sh);
  *reinterpret_cast<float4*>(A + ((size_t)(n*64+c)*16+s)*3136 + y*56 + w4) = v;
}

__global__ void __launch_bounds__(256) kern_scat2(
    const float* __restrict__ C, const float* __restrict__ osc,
    const float* __restrict__ osh, float* __restrict__ A)
{
  __shared__ float tile[56*17];
  const int bid = blockIdx.x;
  const int y = bid % 56, c = (bid/56) & 63, n = bid / 3584;
  const float sc = osc[c], sh = osh[c];
  const size_t cb = ((size_t)(n*56+y)*56)*1024 + c*16;
  for (int e = threadIdx.x; e < 896; e += 256) {
    int w = e >> 4, s = e & 15;
    tile[w*17+s] = C[cb + (size_t)w*1024 + s];
  }
  __syncthreads();
  const size_t ab = (size_t)(n*64+c)*16*3136 + y*56;
  for (int e = threadIdx.x; e < 896; e += 256) {
    int s = e/56, w = e%56;
    A[ab + (size_t)s*3136 + w] = fmaf(tile[w*17+s], sc, sh);
  }
}

// ---------------- final: relu(bn2(U) + identity), bn2 finalize folded ----------------
__global__ void __launch_bounds__(256) kern_final(
    float* __restrict__ U, const float* __restrict__ x,
    const float* __restrict__ st2, const float* __restrict__ g2,
    const float* __restrict__ b2, float* __restrict__ out)
{
  __shared__ float scs[128], shs[128];
  const int t = threadIdx.x;
  if (t < 128) {
    float mean = st2[t]*INVP;
    float var  = st2[128+t]*INVP - mean*mean;
    float sc   = g2[t]*rsqrtf(var + EPSV);
    scs[t] = sc; shs[t] = b2[t] - mean*sc;
  }
  __syncthreads();
  const int idx = blockIdx.x*256 + t;
  if (idx >= P*128/4) return;
  const int e = idx*4;
  const int o = (e / SP) & 127;
  float4 u  = *reinterpret_cast<const float4*>(U + e);
  float4 xv = *reinterpret_cast<const float4*>(x + e);
  const float s = scs[o], h = shs[o];
  float4 r;
  r.x = fmaxf(fmaf(u.x, s, h) + xv.x, 0.f);
  r.y = fmaxf(fmaf(u.y, s, h) + xv.y, 0.f);
  r.z = fmaxf(fmaf(u.z, s, h) + xv.z, 0.f);
  r.w = fmaxf(fmaf(u.w, s, h) + xv.w, 0.f);
  *reinterpret_cast<float4*>(out + e) = r;
}

extern "C" void kernel_launch(void* const* d_in, const int* in_sizes, int n_in,
                              void* d_out, int out_size, void* d_ws, size_t ws_size,
                              hipStream_t stream)
{
  const float* x    = (const float*)d_in[0];
  const float* cdw  = (const float*)d_in[1];
  const float* bn1g = (const float*)d_in[2];
  const float* bn1b = (const float*)d_in[3];
  const float* qkvw = (const float*)d_in[4];
  const float* bnqg = (const float*)d_in[5];
  const float* bnqb = (const float*)d_in[6];
  const float* bnsg = (const float*)d_in[7];
  const float* bnsb = (const float*)d_in[8];
  const float* bnog = (const float*)d_in[9];
  const float* bnob = (const float*)d_in[10];
  const float* cuw  = (const float*)d_in[11];
  const float* bn2g = (const float*)d_in[12];
  const float* bn2b = (const float*)d_in[13];
  float* out = (float*)d_out;
  float* ws  = (float*)d_ws;

  float* A   = ws + OFF_A;
  float* C   = ws + OFF_C;
  float* st  = ws + OFF_ST;
  float* Pp1 = ws + OFF_P1;
  float* Pp2 = ws + OFF_P2;
  float* Bq  = out;

  hipMemsetAsync(st, 0, 4096*sizeof(float), stream);

  // stage A: down-proj (bn1 raw sums into st[0..127])
  kern_down<<<P/128, 256, 0, stream>>>(x, cdw, A, st);

  // direction 0: 'x'
  {
    float* stq = st + 256; float* sts = stq + 512; float* sto = stq + 544;
    kern_tr<<<2048, 256, 0, stream>>>(A, C);
    kern_qkv<true><<<896, 256, 0, stream>>>(C, qkvw, st, bn1g, bn1b, Bq, stq);
    kern_pass1<56><<<3584, 256, 0, stream>>>(Bq, stq, bnqg, bnqb, Pp1);
    kern_redfin<<<8, 256, 0, stream>>>(Pp1, bnsg, bnsb, sts, 3584, 8, 1.f/5619712.f);
    kern_attn<56><<<3584, 256, 0, stream>>>(Bq, stq, bnqg, bnqb, sts, C, Pp2);
    kern_redfin<<<64, 256, 0, stream>>>(Pp2, bnog, bnob, sto, 3584, 64, INVP);
    kern_scat0<<<2048, 256, 0, stream>>>(C, sto, sto+64, A);
  }
  // direction 1: 'y'
  {
    float* stq = st + 256 + 1024; float* sts = stq + 512; float* sto = stq + 544;
    kern_qkv<false><<<896, 256, 0, stream>>>(A, qkvw+8192, st, bn1g, bn1b, Bq, stq);
    kern_pass1<56><<<3584, 256, 0, stream>>>(Bq, stq, bnqg+128, bnqb+128, Pp1);
    kern_redfin<<<8, 256, 0, stream>>>(Pp1, bnsg+8, bnsb+8, sts, 3584, 8, 1.f/5619712.f);
    kern_attn<56><<<3584, 256, 0, stream>>>(Bq, stq, bnqg+128, bnqb+128, sts, C, Pp2);
    kern_redfin<<<64, 256, 0, stream>>>(Pp2, bnog+64, bnob+64, sto, 3584, 64, INVP);
    kern_scat1<<<6272, 256, 0, stream>>>(C, sto, sto+64, A);
  }
  // direction 2: 'seq'
  {
    float* stq = st + 256 + 2048; float* sts = stq + 512; float* sto = stq + 544;
    kern_tr2<<<512, 256, 0, stream>>>(A, C);
    kern_qkv2<<<784, 256, 0, stream>>>(C, qkvw+16384, Bq, stq);
    kern_pass1<16><<<3136, 256, 0, stream>>>(Bq, stq, bnqg+256, bnqb+256, Pp1);
    kern_redfin<<<8, 256, 0, stream>>>(Pp1, bnsg+16, bnsb+16, sts, 3136, 8, 1.f/1605632.f);
    kern_attn<16><<<3136, 256, 0, stream>>>(Bq, stq, bnqg+256, bnqb+256, sts, C, Pp2);
    kern_redfin<<<64, 256, 0, stream>>>(Pp2, bnog+128, bnob+128, sto, 3136, 64, INVP);
    kern_scat2<<<7168, 256, 0, stream>>>(C, sto, sto+64, A);
  }

  // stage B: relu -> up-proj (bn2 raw sums) -> residual + relu (bn2 folded)
  float* st2 = st + 3328;
  kern_up<<<P/128, 256, 0, stream>>>(A, cuw, Bq, st2);
  kern_final<<<P*128/4/256, 256, 0, stream>>>(Bq, x, st2, bn2g, bn2b, out);
}